// Round 11
// baseline (154.498 us; speedup 1.0000x reference)
//
#include <hip/hip_runtime.h>
#include <math.h>

#define NTOK 16384
#define DIM  4096
#define NE   64
#define TOPK 8
#define TPB  32                  // tokens per block
#define CHUNK 64                 // f32 per row per chunk (16 granules of 16B)
#define NCH  (DIM / CHUNK)       // 64 chunks, 2 k32-slices each
#define NB   5                   // LDS ring buffers (4 in flight + 1 consuming)
#define ROUTE_SCALE 2.5f

typedef __attribute__((ext_vector_type(8))) short short8v;
typedef __attribute__((ext_vector_type(4))) float f32x4;

// exact 3-term bf16 truncation split of 8 f32, packed as 3x short8 (bf16) frags
__device__ __forceinline__ void split3_pack(const float* v, uint4& b0, uint4& b1, uint4& b2)
{
    uint p0[8], p1[8], p2[8];
#pragma unroll
    for (int j = 0; j < 8; ++j) {
        const float xv = v[j];
        const uint  u0 = __float_as_uint(xv) & 0xffff0000u;
        const float f0 = __uint_as_float(u0);
        const float r  = xv - f0;                       // exact
        const uint  u1 = __float_as_uint(r) & 0xffff0000u;
        const float f1 = __uint_as_float(u1);
        const float r2 = r - f1;                        // exact, fits bf16
        const uint  u2 = __float_as_uint(r2) & 0xffff0000u;
        p0[j] = u0; p1[j] = u1; p2[j] = u2;
    }
    b0 = make_uint4(p0[1] | (p0[0] >> 16), p0[3] | (p0[2] >> 16),
                    p0[5] | (p0[4] >> 16), p0[7] | (p0[6] >> 16));
    b1 = make_uint4(p1[1] | (p1[0] >> 16), p1[3] | (p1[2] >> 16),
                    p1[5] | (p1[4] >> 16), p1[7] | (p1[6] >> 16));
    b2 = make_uint4(p2[1] | (p2[0] >> 16), p2[3] | (p2[2] >> 16),
                    p2[5] | (p2[4] >> 16), p2[7] | (p2[6] >> 16));
}

// ---- prep: w -> frag-ready bf16 splits (UNCHANGED, proven r4-r10) ----
__global__ __launch_bounds__(256)
void prep_w(const float* __restrict__ gw, uint4* __restrict__ wS)
{
    const int tid  = blockIdx.x * 256 + threadIdx.x;   // 32768 total
    const int lane = tid & 63;
    const int nt   = (tid >> 6) & 3;
    const int ks   = tid >> 8;                         // 0..127
    const int e    = nt * 16 + (lane & 15);
    const int kb   = ks * 32 + (lane >> 4) * 8;
    float v[8];
    *(float4*)&v[0] = *(const float4*)&gw[(size_t)e * DIM + kb];
    *(float4*)&v[4] = *(const float4*)&gw[(size_t)e * DIM + kb + 4];
    uint4 b0, b1, b2;
    split3_pack(v, b0, b1, b2);
    const size_t base = (size_t)(ks * 4 + nt) * 3 * 64 + lane;
    wS[base] = b0; wS[base + 64] = b1; wS[base + 128] = b2;
}

__device__ __forceinline__ void gld_lds16(const float* g, float* l)
{
    __builtin_amdgcn_global_load_lds(
        (const __attribute__((address_space(1))) unsigned int*)g,
        (__attribute__((address_space(3))) unsigned int*)l,
        16, 0, 0);
}

#define MFMA6(A0, A1, A2, B0, B1, B2, ACC) do {                              \
    ACC = __builtin_amdgcn_mfma_f32_16x16x32_bf16(A2, B0, ACC, 0, 0, 0);     \
    ACC = __builtin_amdgcn_mfma_f32_16x16x32_bf16(A1, B1, ACC, 0, 0, 0);     \
    ACC = __builtin_amdgcn_mfma_f32_16x16x32_bf16(A0, B2, ACC, 0, 0, 0);     \
    ACC = __builtin_amdgcn_mfma_f32_16x16x32_bf16(A1, B0, ACC, 0, 0, 0);     \
    ACC = __builtin_amdgcn_mfma_f32_16x16x32_bf16(A0, B1, ACC, 0, 0, 0);     \
    ACC = __builtin_amdgcn_mfma_f32_16x16x32_bf16(A0, B0, ACC, 0, 0, 0);     \
} while (0)

#define WAITV(N) do { asm volatile("s_waitcnt vmcnt(" #N ")" ::: "memory"); \
                      __builtin_amdgcn_sched_barrier(0); } while (0)
#define BAR     do { __builtin_amdgcn_sched_barrier(0);                     \
                     __builtin_amdgcn_s_barrier();                          \
                     __builtin_amdgcn_sched_barrier(0); } while (0)

// ---- fused: 4-wave WG, 32 tokens, wave = expert quarter; 4-deep unified FIFO ----
__global__ __launch_bounds__(256)
void router_fused(const float* __restrict__ x, const uint4* __restrict__ wS,
                  const float* __restrict__ bias, float* __restrict__ out)
{
    __shared__ float raw[NB][TPB][CHUNK];   // 40 KB ring, linear (DMA dest)
    __shared__ float sc[TPB][NE + 1];       // 8.3 KB
    __shared__ int   hist[NE];

    const int t    = threadIdx.x;
    const int lane = t & 63;
    const int wv   = __builtin_amdgcn_readfirstlane(t >> 6);   // 0..3 expert quarter
    const int r15  = lane & 15;
    const int g    = lane >> 4;
    const int tok0 = blockIdx.x * TPB;

    if (t < NE) hist[t] = 0;

    // DMA op j (j=0,1): LDS pos p=(wv*2+j)*64+lane holds granule gl=(p&15)^(r&15) of row r=p>>4
    const int r0  = (wv * 2 + 0) * 4 + (lane >> 4);
    const int r1  = (wv * 2 + 1) * 4 + (lane >> 4);
    const int gl0 = (lane & 15) ^ (r0 & 15);
    const int gl1 = (lane & 15) ^ (r1 & 15);
    const float* gsrc0 = x + (size_t)(tok0 + r0) * DIM + gl0 * 4;
    const float* gsrc1 = x + (size_t)(tok0 + r1) * DIM + gl1 * 4;
    float* ldst0 = &raw[0][(wv * 2 + 0) * 4][0];   // wave-uniform bases (buf 0)
    float* ldst1 = &raw[0][(wv * 2 + 1) * 4][0];

    const uint4* wB = wS + (size_t)wv * 192 + lane;

    f32x4 acc0 = {0.f, 0.f, 0.f, 0.f};
    f32x4 acc1 = {0.f, 0.f, 0.f, 0.f};
    uint4 Br0[6], Br1[6], Br2[6], Br3[6];   // static 4-slot B ring (4-deep FIFO)

#define DMA2(c, b) do {                                                      \
        gld_lds16(gsrc0 + (size_t)(c) * CHUNK, ldst0 + (size_t)(b) * TPB * CHUNK); \
        gld_lds16(gsrc1 + (size_t)(c) * CHUNK, ldst1 + (size_t)(b) * TPB * CHUNK); \
    } while (0)
#define LOADB(B, c1) do {                                                    \
        _Pragma("unroll")                                                    \
        for (int s2 = 0; s2 < 2; ++s2)                                       \
            _Pragma("unroll")                                                \
            for (int sp = 0; sp < 3; ++sp)                                   \
                B[s2 * 3 + sp] = wB[(size_t)(2 * (c1) + s2) * 768 + sp * 64];\
    } while (0)
#define SLICE_C(rp, B, s) do {                                               \
        const int gA = (s) * 8 + g * 2;                                      \
        float a8[8]; uint4 a0u, a1u, a2u;                                    \
        *(float4*)&a8[0] = *(const float4*)(rp + r15 * CHUNK + (gA ^ r15) * 4);        \
        *(float4*)&a8[4] = *(const float4*)(rp + r15 * CHUNK + ((gA + 1) ^ r15) * 4);  \
        split3_pack(a8, a0u, a1u, a2u);                                      \
        MFMA6(*(short8v*)&a0u, *(short8v*)&a1u, *(short8v*)&a2u,             \
              *(const short8v*)&B[(s)*3+0], *(const short8v*)&B[(s)*3+1],    \
              *(const short8v*)&B[(s)*3+2], acc0);                           \
        *(float4*)&a8[0] = *(const float4*)(rp + (16 + r15) * CHUNK + (gA ^ r15) * 4);       \
        *(float4*)&a8[4] = *(const float4*)(rp + (16 + r15) * CHUNK + ((gA + 1) ^ r15) * 4); \
        split3_pack(a8, a0u, a1u, a2u);                                      \
        MFMA6(*(short8v*)&a0u, *(short8v*)&a1u, *(short8v*)&a2u,             \
              *(const short8v*)&B[(s)*3+0], *(const short8v*)&B[(s)*3+1],    \
              *(const short8v*)&B[(s)*3+2], acc1);                           \
    } while (0)
#define COMPCHUNK(bix, B) do {                                               \
        const float* rp = &raw[bix][0][0];                                   \
        SLICE_C(rp, B, 0);                                                   \
        SLICE_C(rp, B, 1);                                                   \
    } while (0)
// one sub-iteration: retire chunk c's group, keep c+1..c+4 in flight
#define SUBITER(c, Bj) do {                                                  \
        WAITV(24); BAR;                                                      \
        DMA2((c) + 4, bd); bd = (bd == NB - 1) ? 0 : bd + 1;                 \
        COMPCHUNK(bi, Bj); bi = (bi == NB - 1) ? 0 : bi + 1;                 \
        LOADB(Bj, (c) + 4);                                                  \
    } while (0)

    // ---- prologue: 4 chunk-groups in FIFO order [DMA:2][B:6] each ----
    int bi = 0, bd = 0;
    DMA2(0, 0); LOADB(Br0, 0);
    DMA2(1, 1); LOADB(Br1, 1);
    DMA2(2, 2); LOADB(Br2, 2);
    DMA2(3, 3); LOADB(Br3, 3);
    bd = 4;

    // ---- main: chunks 0..59, issuing 4..63 (unroll-4 keeps B ring static) ----
#pragma unroll 1
    for (int c = 0; c < 60; c += 4) {
        SUBITER(c + 0, Br0);
        SUBITER(c + 1, Br1);
        SUBITER(c + 2, Br2);
        SUBITER(c + 3, Br3);
    }
    // ---- tail: chunks 60..63, draining 24/16/8/0 ----
    WAITV(24); BAR; COMPCHUNK(bi, Br0); bi = (bi == NB - 1) ? 0 : bi + 1;
    WAITV(16); BAR; COMPCHUNK(bi, Br1); bi = (bi == NB - 1) ? 0 : bi + 1;
    WAITV(8);  BAR; COMPCHUNK(bi, Br2); bi = (bi == NB - 1) ? 0 : bi + 1;
    WAITV(0);  BAR; COMPCHUNK(bi, Br3);

#undef DMA2
#undef LOADB
#undef SLICE_C
#undef COMPCHUNK
#undef SUBITER

    // ---- scores (C/D layout proven r4-r10: token = g*4+q, expert = wv*16+r15) ----
#pragma unroll
    for (int q = 0; q < 4; ++q) {
        sc[g * 4 + q][wv * 16 + r15]      = 1.f / (1.f + expf(-acc0[q]));
        sc[16 + g * 4 + q][wv * 16 + r15] = 1.f / (1.f + expf(-acc1[q]));
    }
    __syncthreads();

    // ---- top-8: wave wv handles tokens wv*8..wv*8+7; lane == expert (proven) ----
    const float bias_l = bias[lane];
#pragma unroll 1
    for (int i = 0; i < 8; ++i) {
        const int tok = wv * 8 + i;
        const float s = sc[tok][lane];
        float myv  = s + bias_l;
        float outv = 0.f;
        int   outi = 0;
        float sum  = 0.f;
#pragma unroll
        for (int k = 0; k < TOPK; ++k) {
            float cv = myv;
            int   ci = lane;
#pragma unroll
            for (int off = 32; off; off >>= 1) {
                float ov = __shfl_xor(cv, off, 64);
                int   oi = __shfl_xor(ci, off, 64);
                if (ov > cv || (ov == cv && oi < ci)) { cv = ov; ci = oi; }
            }
            float ts = __shfl(s, ci, 64);      // unbiased score of winner
            sum += ts;
            if (lane == k)  { outv = ts; outi = ci; }
            if (lane == ci) { myv = -1e30f; }
        }
        const float denom = sum + 1e-20f;
        const size_t gt = (size_t)tok0 + tok;
        if (lane < TOPK) {
            out[gt * TOPK + lane] = (outv / denom) * ROUTE_SCALE;
            out[(size_t)NTOK * TOPK + gt * TOPK + lane] = (float)outi;
            atomicAdd(&hist[outi], 1);
        }
    }

    __syncthreads();
    if (t < NE) {
        int cgt = hist[t];
        if (cgt) atomicAdd(&out[(size_t)NTOK * TOPK * 2 + t], (float)cgt);
    }
}

extern "C" void kernel_launch(void* const* d_in, const int* in_sizes, int n_in,
                              void* d_out, int out_size, void* d_ws, size_t ws_size,
                              hipStream_t stream)
{
    const float* x    = (const float*)d_in[0];
    const float* gw   = (const float*)d_in[1];
    const float* bias = (const float*)d_in[2];
    float* out = (float*)d_out;
    uint4* wS  = (uint4*)d_ws;   // 1.5 MB

    // histogram region must start at zero every call
    hipMemsetAsync(out + (size_t)NTOK * TOPK * 2, 0, NE * sizeof(float), stream);

    prep_w<<<128, 256, 0, stream>>>(gw, wS);
    router_fused<<<NTOK / TPB, 256, 0, stream>>>(x, wS, bias, out);
}

// Round 12
// 148.379 us; speedup vs baseline: 1.0412x; 1.0412x over previous
//
#include <hip/hip_runtime.h>
#include <math.h>

#define NTOK 16384
#define DIM  4096
#define NE   64
#define TOPK 8
#define TPB  32                  // tokens per block
#define CHUNK 128                // f32 per row per chunk (512B row bursts)
#define NCH  (DIM / CHUNK)       // 32 chunks, 4 k32-slices each
#define NB   3                   // LDS ring buffers
#define PAIRF 260                // floats per token-pair: 2*128 + 4 pad
#define ROUTE_SCALE 2.5f

typedef __attribute__((ext_vector_type(8))) short short8v;
typedef __attribute__((ext_vector_type(4))) float f32x4;

// exact 3-term bf16 truncation split of 8 f32, packed as 3x short8 (bf16) frags
__device__ __forceinline__ void split3_pack(const float* v, uint4& b0, uint4& b1, uint4& b2)
{
    uint p0[8], p1[8], p2[8];
#pragma unroll
    for (int j = 0; j < 8; ++j) {
        const float xv = v[j];
        const uint  u0 = __float_as_uint(xv) & 0xffff0000u;
        const float f0 = __uint_as_float(u0);
        const float r  = xv - f0;                       // exact
        const uint  u1 = __float_as_uint(r) & 0xffff0000u;
        const float f1 = __uint_as_float(u1);
        const float r2 = r - f1;                        // exact, fits bf16
        const uint  u2 = __float_as_uint(r2) & 0xffff0000u;
        p0[j] = u0; p1[j] = u1; p2[j] = u2;
    }
    b0 = make_uint4(p0[1] | (p0[0] >> 16), p0[3] | (p0[2] >> 16),
                    p0[5] | (p0[4] >> 16), p0[7] | (p0[6] >> 16));
    b1 = make_uint4(p1[1] | (p1[0] >> 16), p1[3] | (p1[2] >> 16),
                    p1[5] | (p1[4] >> 16), p1[7] | (p1[6] >> 16));
    b2 = make_uint4(p2[1] | (p2[0] >> 16), p2[3] | (p2[2] >> 16),
                    p2[5] | (p2[4] >> 16), p2[7] | (p2[6] >> 16));
}

// ---- prep: w -> frag-ready bf16 splits (UNCHANGED, proven r4-r11) ----
__global__ __launch_bounds__(256)
void prep_w(const float* __restrict__ gw, uint4* __restrict__ wS)
{
    const int tid  = blockIdx.x * 256 + threadIdx.x;   // 32768 total
    const int lane = tid & 63;
    const int nt   = (tid >> 6) & 3;
    const int ks   = tid >> 8;                         // 0..127
    const int e    = nt * 16 + (lane & 15);
    const int kb   = ks * 32 + (lane >> 4) * 8;
    float v[8];
    *(float4*)&v[0] = *(const float4*)&gw[(size_t)e * DIM + kb];
    *(float4*)&v[4] = *(const float4*)&gw[(size_t)e * DIM + kb + 4];
    uint4 b0, b1, b2;
    split3_pack(v, b0, b1, b2);
    const size_t base = (size_t)(ks * 4 + nt) * 3 * 64 + lane;
    wS[base] = b0; wS[base + 64] = b1; wS[base + 128] = b2;
}

__device__ __forceinline__ void gld_lds16(const float* g, float* l)
{
    __builtin_amdgcn_global_load_lds(
        (const __attribute__((address_space(1))) unsigned int*)g,
        (__attribute__((address_space(3))) unsigned int*)l,
        16, 0, 0);
}

#define MFMA6(A0, A1, A2, B0, B1, B2, ACC) do {                              \
    ACC = __builtin_amdgcn_mfma_f32_16x16x32_bf16(A2, B0, ACC, 0, 0, 0);     \
    ACC = __builtin_amdgcn_mfma_f32_16x16x32_bf16(A1, B1, ACC, 0, 0, 0);     \
    ACC = __builtin_amdgcn_mfma_f32_16x16x32_bf16(A0, B2, ACC, 0, 0, 0);     \
    ACC = __builtin_amdgcn_mfma_f32_16x16x32_bf16(A1, B0, ACC, 0, 0, 0);     \
    ACC = __builtin_amdgcn_mfma_f32_16x16x32_bf16(A0, B1, ACC, 0, 0, 0);     \
    ACC = __builtin_amdgcn_mfma_f32_16x16x32_bf16(A0, B0, ACC, 0, 0, 0);     \
} while (0)

#define WAITV(N) do { asm volatile("s_waitcnt vmcnt(" #N ")" ::: "memory"); \
                      __builtin_amdgcn_sched_barrier(0); } while (0)
#define BAR     do { __builtin_amdgcn_sched_barrier(0);                     \
                     __builtin_amdgcn_s_barrier();                          \
                     __builtin_amdgcn_sched_barrier(0); } while (0)

// ---- fused: 4-wave WG, 32 tokens, wave = expert quarter ----
// x staged by DMA in CONTIGUOUS 512B row bursts (no source permutation);
// pad-pair LDS layout (no swizzle); 2-deep counted-vmcnt ring (m201 shape).
__global__ __launch_bounds__(256)
void router_fused(const float* __restrict__ x, const uint4* __restrict__ wS,
                  const float* __restrict__ bias, float* __restrict__ out)
{
    __shared__ __align__(16) float raw[NB][16][PAIRF];   // 49.9 KB ring (DMA dest)
    __shared__ float sc[TPB][NE + 1];                    // 8.3 KB
    __shared__ int   hist[NE];

    const int t    = threadIdx.x;
    const int lane = t & 63;
    const int wv   = __builtin_amdgcn_readfirstlane(t >> 6);   // 0..3 expert quarter
    const int r15  = lane & 15;
    const int g    = lane >> 4;
    const int tok0 = blockIdx.x * TPB;

    if (t < NE) hist[t] = 0;

    // DMA op o (0..3): pair p = wv*4+o (tokens 2p,2p+1).
    // lanes 0-31 -> row 2p bytes [c*512, c*512+512); lanes 32-63 -> row 2p+1. Fully linear.
    const float* gsrc0 = x + (size_t)(tok0 + 2 * (wv * 4 + 0) + (lane >> 5)) * DIM + (lane & 31) * 4;
    const float* gsrc1 = x + (size_t)(tok0 + 2 * (wv * 4 + 1) + (lane >> 5)) * DIM + (lane & 31) * 4;
    const float* gsrc2 = x + (size_t)(tok0 + 2 * (wv * 4 + 2) + (lane >> 5)) * DIM + (lane & 31) * 4;
    const float* gsrc3 = x + (size_t)(tok0 + 2 * (wv * 4 + 3) + (lane >> 5)) * DIM + (lane & 31) * 4;

    const uint4* wB = wS + (size_t)wv * 192 + lane;

    f32x4 acc0 = {0.f, 0.f, 0.f, 0.f};
    f32x4 acc1 = {0.f, 0.f, 0.f, 0.f};
    uint4 Bev[12], Bod[12];    // 2-slot static B ring (distance-2 FIFO)

#define DMAC(c, b) do {                                                      \
        gld_lds16(gsrc0 + (size_t)(c) * CHUNK, &raw[b][wv * 4 + 0][0]);      \
        gld_lds16(gsrc1 + (size_t)(c) * CHUNK, &raw[b][wv * 4 + 1][0]);      \
        gld_lds16(gsrc2 + (size_t)(c) * CHUNK, &raw[b][wv * 4 + 2][0]);      \
        gld_lds16(gsrc3 + (size_t)(c) * CHUNK, &raw[b][wv * 4 + 3][0]);      \
    } while (0)
#define LOADB(B, c1) do {                                                    \
        _Pragma("unroll")                                                    \
        for (int s2 = 0; s2 < 4; ++s2)                                       \
            _Pragma("unroll")                                                \
            for (int sp = 0; sp < 3; ++sp)                                   \
                B[s2 * 3 + sp] = wB[(size_t)((c1) * 4 + s2) * 768 + sp * 64];\
    } while (0)
// A-frag read: row r -> pair r>>1 (stride 260 floats), sub-row (r&1)*128. 2-way banks.
#define SLICE_C(rp, B, s) do {                                               \
        const int ko   = (s) * 32 + g * 8;                                   \
        const int off0 = (r15 >> 1) * PAIRF + (r15 & 1) * CHUNK + ko;        \
        float a8[8]; uint4 a0u, a1u, a2u;                                    \
        *(float4*)&a8[0] = *(const float4*)(rp + off0);                      \
        *(float4*)&a8[4] = *(const float4*)(rp + off0 + 4);                  \
        split3_pack(a8, a0u, a1u, a2u);                                      \
        MFMA6(*(short8v*)&a0u, *(short8v*)&a1u, *(short8v*)&a2u,             \
              *(const short8v*)&B[(s)*3+0], *(const short8v*)&B[(s)*3+1],    \
              *(const short8v*)&B[(s)*3+2], acc0);                           \
        *(float4*)&a8[0] = *(const float4*)(rp + off0 + 8 * PAIRF);          \
        *(float4*)&a8[4] = *(const float4*)(rp + off0 + 8 * PAIRF + 4);      \
        split3_pack(a8, a0u, a1u, a2u);                                      \
        MFMA6(*(short8v*)&a0u, *(short8v*)&a1u, *(short8v*)&a2u,             \
              *(const short8v*)&B[(s)*3+0], *(const short8v*)&B[(s)*3+1],    \
              *(const short8v*)&B[(s)*3+2], acc1);                           \
    } while (0)
#define COMPCHUNK(bix, B) do {                                               \
        const float* rp = &raw[bix][0][0];                                   \
        SLICE_C(rp, B, 0); SLICE_C(rp, B, 1);                                \
        SLICE_C(rp, B, 2); SLICE_C(rp, B, 3);                                \
    } while (0)

    // ---- prologue: 2 chunk-groups of [DMA:4][B:12] = 16 ops each ----
    int bi = 0, bd = 2;
    DMAC(0, 0); LOADB(Bev, 0);
    DMAC(1, 1); LOADB(Bod, 1);

    // ---- main: chunks 0..29, issuing 2..31; group c retired by vmcnt(16) ----
#pragma unroll 1
    for (int c = 0; c < NCH - 2; c += 2) {
        WAITV(16); BAR;
        DMAC(c + 2, bd); bd = (bd == NB - 1) ? 0 : bd + 1;
        COMPCHUNK(bi, Bev); bi = (bi == NB - 1) ? 0 : bi + 1;
        LOADB(Bev, c + 2);                 // after consume: no reg-WAR, FIFO group intact
        WAITV(16); BAR;
        DMAC(c + 3, bd); bd = (bd == NB - 1) ? 0 : bd + 1;
        COMPCHUNK(bi, Bod); bi = (bi == NB - 1) ? 0 : bi + 1;
        LOADB(Bod, c + 3);
    }
    // ---- tail: chunks 30, 31 ----
    WAITV(16); BAR; COMPCHUNK(bi, Bev); bi = (bi == NB - 1) ? 0 : bi + 1;
    WAITV(0);  BAR; COMPCHUNK(bi, Bod);

#undef DMAC
#undef LOADB
#undef SLICE_C
#undef COMPCHUNK

    // ---- scores (C/D layout proven r4-r11: token = g*4+q, expert = wv*16+r15) ----
#pragma unroll
    for (int q = 0; q < 4; ++q) {
        sc[g * 4 + q][wv * 16 + r15]      = 1.f / (1.f + expf(-acc0[q]));
        sc[16 + g * 4 + q][wv * 16 + r15] = 1.f / (1.f + expf(-acc1[q]));
    }
    __syncthreads();

    // ---- top-8: wave wv handles tokens wv*8..wv*8+7; lane == expert (proven) ----
    const float bias_l = bias[lane];
#pragma unroll 1
    for (int i = 0; i < 8; ++i) {
        const int tok = wv * 8 + i;
        const float s = sc[tok][lane];
        float myv  = s + bias_l;
        float outv = 0.f;
        int   outi = 0;
        float sum  = 0.f;
#pragma unroll
        for (int k = 0; k < TOPK; ++k) {
            float cv = myv;
            int   ci = lane;
#pragma unroll
            for (int off = 32; off; off >>= 1) {
                float ov = __shfl_xor(cv, off, 64);
                int   oi = __shfl_xor(ci, off, 64);
                if (ov > cv || (ov == cv && oi < ci)) { cv = ov; ci = oi; }
            }
            float ts = __shfl(s, ci, 64);      // unbiased score of winner
            sum += ts;
            if (lane == k)  { outv = ts; outi = ci; }
            if (lane == ci) { myv = -1e30f; }
        }
        const float denom = sum + 1e-20f;
        const size_t gt = (size_t)tok0 + tok;
        if (lane < TOPK) {
            out[gt * TOPK + lane] = (outv / denom) * ROUTE_SCALE;
            out[(size_t)NTOK * TOPK + gt * TOPK + lane] = (float)outi;
            atomicAdd(&hist[outi], 1);
        }
    }

    __syncthreads();
    if (t < NE) {
        int cgt = hist[t];
        if (cgt) atomicAdd(&out[(size_t)NTOK * TOPK * 2 + t], (float)cgt);
    }
}

extern "C" void kernel_launch(void* const* d_in, const int* in_sizes, int n_in,
                              void* d_out, int out_size, void* d_ws, size_t ws_size,
                              hipStream_t stream)
{
    const float* x    = (const float*)d_in[0];
    const float* gw   = (const float*)d_in[1];
    const float* bias = (const float*)d_in[2];
    float* out = (float*)d_out;
    uint4* wS  = (uint4*)d_ws;   // 1.5 MB

    // histogram region must start at zero every call
    hipMemsetAsync(out + (size_t)NTOK * TOPK * 2, 0, NE * sizeof(float), stream);

    prep_w<<<128, 256, 0, stream>>>(gw, wS);
    router_fused<<<NTOK / TPB, 256, 0, stream>>>(x, wS, bias, out);
}